// Round 3
// baseline (504.614 us; speedup 1.0000x reference)
//
#include <hip/hip_runtime.h>
#include <hip/hip_bf16.h>
#include <cstdint>

typedef unsigned short u16;
typedef unsigned int u32;
typedef __bf16 bf16x8 __attribute__((ext_vector_type(8)));
typedef u16 u16x8 __attribute__((ext_vector_type(8)));
typedef float f32x4 __attribute__((ext_vector_type(4)));

#define MFMA16(a, b, c) __builtin_amdgcn_mfma_f32_16x16x32_bf16(a, b, c, 0, 0, 0)

__device__ __forceinline__ u16 f2bf(float f) {
    u32 u; __builtin_memcpy(&u, &f, 4);
    u = u + 0x7fffu + ((u >> 16) & 1u);
    return (u16)(u >> 16);
}

// ---------------------------------------------------------------------------
// f32 -> bf16 convert, 8 elems/thread. n8 = n/8 (n divisible by 8).
// ---------------------------------------------------------------------------
__global__ __launch_bounds__(256) void convert_f32_bf16(const float* __restrict__ in,
                                                        u16* __restrict__ out, int n8) {
    const int i = blockIdx.x * 256 + threadIdx.x;
    if (i >= n8) return;
    const float4* p = (const float4*)in + (size_t)i * 2;
    const float4 a = p[0], b = p[1];
    u16x8 v;
    v[0] = f2bf(a.x); v[1] = f2bf(a.y); v[2] = f2bf(a.z); v[3] = f2bf(a.w);
    v[4] = f2bf(b.x); v[5] = f2bf(b.y); v[6] = f2bf(b.z); v[7] = f2bf(b.w);
    ((u16x8*)out)[i] = v;
}

// ---------------------------------------------------------------------------
// f32 (R x C) row-major -> bf16 (C x R) row-major transpose.
// ---------------------------------------------------------------------------
__global__ __launch_bounds__(256) void transpose_f32_bf16(const float* __restrict__ in,
                                                          u16* __restrict__ out,
                                                          int R, int C) {
    __shared__ u16 t[64][65];
    const int r0 = blockIdx.y << 6, c0 = blockIdx.x << 6;
    const int tid = threadIdx.x;
#pragma unroll
    for (int i = 0; i < 16; i++) {
        int idx = i * 256 + tid;
        int r = idx >> 6, c = idx & 63;
        t[r][c] = f2bf(in[(size_t)(r0 + r) * C + c0 + c]);
    }
    __syncthreads();
#pragma unroll
    for (int i = 0; i < 16; i++) {
        int idx = i * 256 + tid;
        int c = idx >> 6, r = idx & 63;
        out[(size_t)(c0 + c) * R + r0 + r] = t[r][c];
    }
}

// ---------------------------------------------------------------------------
// V transpose: kv (B,K,H,256)[e>=128] -> vT (B,H,128,K)   (bf16 -> bf16)
// grid: B*H*(K/64) = 2048 blocks, 256 threads
// ---------------------------------------------------------------------------
__global__ __launch_bounds__(256) void transpose_v(const u16* __restrict__ kv,
                                                   u16* __restrict__ vT) {
    __shared__ u16 t[64][130];
    const int blk = blockIdx.x;
    const int kt = blk & 63, h = (blk >> 6) & 7, b = blk >> 9;
    const int k0 = kt * 64, tid = threadIdx.x;
    const u16* src = kv + ((size_t)(b * 4096 + k0) * 8 + h) * 256 + 128;
#pragma unroll
    for (int i = 0; i < 16; i++) {
        int idx = i * 256 + tid;          // u32 units, 0..4095
        int ki = idx >> 6, e2 = (idx & 63) << 1;
        u32 v = *(const u32*)(src + (size_t)ki * 2048 + e2);
        t[ki][e2] = (u16)v; t[ki][e2 + 1] = (u16)(v >> 16);
    }
    __syncthreads();
    u16* dst = vT + ((size_t)(b * 8 + h)) * 128 * 4096 + k0;
#pragma unroll
    for (int i = 0; i < 16; i++) {
        int idx = i * 256 + tid;
        int e = idx >> 5, ki2 = (idx & 31) << 1;
        u32 v = (u32)t[ki2][e] | ((u32)t[ki2 + 1][e] << 16);
        *(u32*)(dst + (size_t)e * 4096 + ki2) = v;
    }
}

// ---------------------------------------------------------------------------
// GEMM: C(MxN) = A(MxK) * B^T(NxK), bf16 in, fp32 acc, out f32 or bf16.
// 128x128 tile, BK=64. grid: (M/128)*(N/128), block 256 (4 waves, 2x2 of 64x64).
// ---------------------------------------------------------------------------
template <bool OUTF32>
__global__ __launch_bounds__(256) void gemm_bt(const u16* __restrict__ A,
                                               const u16* __restrict__ B,
                                               void* __restrict__ Cv,
                                               const float* __restrict__ bias,
                                               int M, int N, int K) {
    __shared__ __align__(16) u16 As[128 * 64];
    __shared__ __align__(16) u16 Bs[128 * 64];
    const int tid = threadIdx.x;
    const int wave = tid >> 6, lane = tid & 63;
    const int lrow = lane & 15, quad = lane >> 4;
    const int nb = N >> 7;
    const int bx = blockIdx.x % nb, by = blockIdx.x / nb;
    const long m0 = (long)by << 7, n0 = (long)bx << 7;
    const int wm = (wave >> 1) << 6, wn = (wave & 1) << 6;

    const f32x4 fz = {0.f, 0.f, 0.f, 0.f};
    f32x4 acc[4][4];
#pragma unroll
    for (int i = 0; i < 4; i++)
#pragma unroll
        for (int j = 0; j < 4; j++) acc[i][j] = fz;

    const int srow = tid >> 3;        // [0,32)
    const int sblk = tid & 7;         // [0,8)

    for (int k0 = 0; k0 < K; k0 += 64) {
        __syncthreads();
#pragma unroll
        for (int i = 0; i < 4; i++) {
            const int row = i * 32 + srow;
            *(bf16x8*)&As[row * 64 + sblk * 8] =
                *(const bf16x8*)&A[(m0 + row) * K + k0 + sblk * 8];
            *(bf16x8*)&Bs[row * 64 + sblk * 8] =
                *(const bf16x8*)&B[(n0 + row) * K + k0 + sblk * 8];
        }
        __syncthreads();
#pragma unroll
        for (int c = 0; c < 2; c++) {
            const int ko = c * 32 + quad * 8;
            bf16x8 af[4], bfr[4];
#pragma unroll
            for (int i = 0; i < 4; i++) {
                af[i]  = *(const bf16x8*)&As[(wm + i * 16 + lrow) * 64 + ko];
                bfr[i] = *(const bf16x8*)&Bs[(wn + i * 16 + lrow) * 64 + ko];
            }
#pragma unroll
            for (int i = 0; i < 4; i++)
#pragma unroll
                for (int j = 0; j < 4; j++)
                    acc[i][j] = MFMA16(af[i], bfr[j], acc[i][j]);
        }
    }
    // epilogue: C/D layout col=lane&15, row=quad*4+r
#pragma unroll
    for (int j = 0; j < 4; j++) {
        const long col = n0 + wn + j * 16 + lrow;
        const float bv = bias ? bias[col] : 0.0f;
#pragma unroll
        for (int i = 0; i < 4; i++) {
            const long row = m0 + wm + i * 16 + quad * 4;
#pragma unroll
            for (int r = 0; r < 4; r++) {
                const float v = acc[i][j][r] + bv;
                if (OUTF32) ((float*)Cv)[(row + r) * N + col] = v;
                else        ((u16*)Cv)[(row + r) * N + col] = f2bf(v);
            }
        }
    }
}

// ---------------------------------------------------------------------------
// Flash attention: q(B,Q,H,128), k from kv(B,K,H,256)[0:128], vT(B,H,128,K)
// -> o(B,Q,H,128).  grid: B*H*(Q/64)=256 blocks, 256 threads (4 waves x 16 q-rows).
// ---------------------------------------------------------------------------
__global__ __launch_bounds__(256) void flash_attn(const u16* __restrict__ qb,
                                                  const u16* __restrict__ kvb,
                                                  const u16* __restrict__ vTb,
                                                  u16* __restrict__ ob) {
    __shared__ __align__(16) u16 Ks[128 * 128];   // rows = kv pos, cols = head dim
    __shared__ __align__(16) u16 Vs[128 * 128];   // rows = head dim, cols = kv-local
    __shared__ __align__(16) u16 Ps[4][16 * 136]; // per-wave P, padded stride
    const int tid = threadIdx.x, wave = tid >> 6, lane = tid & 63;
    const int lrow = lane & 15, quad = lane >> 4;
    const int blk = blockIdx.x;
    const int qt = blk & 7, h = (blk >> 3) & 7, b = blk >> 6;
    const int q0 = qt * 64;

    // persistent q A-frags: A[m=lrow][k=quad*8+c*32+j]
    bf16x8 qf[4];
    {
        const u16* qp = qb + (((size_t)(b * 512 + q0 + wave * 16 + lrow) * 8 + h) << 7) + quad * 8;
#pragma unroll
        for (int c = 0; c < 4; c++) qf[c] = *(const bf16x8*)(qp + c * 32);
    }

    const f32x4 fz = {0.f, 0.f, 0.f, 0.f};
    f32x4 oacc[8];
#pragma unroll
    for (int n = 0; n < 8; n++) oacc[n] = fz;
    float mrow[4] = {-1e30f, -1e30f, -1e30f, -1e30f};
    float lsum[4] = {0.f, 0.f, 0.f, 0.f};
    const float scale = 0.08838834764831845f;  // 1/sqrt(128)

    const int srow = tid >> 4;        // [0,16)
    const int sblk = tid & 15;        // [0,16)
    const u16* kg = kvb + (size_t)b * 4096 * 2048 + h * 256 + sblk * 8;
    const u16* vg = vTb + (size_t)(b * 8 + h) * 128 * 4096 + sblk * 8;

    for (int k0 = 0; k0 < 4096; k0 += 128) {
        __syncthreads();
#pragma unroll
        for (int i = 0; i < 8; i++) {
            const int row = i * 16 + srow;
            *(bf16x8*)&Ks[row * 128 + sblk * 8] =
                *(const bf16x8*)&kg[(size_t)(k0 + row) * 2048];
            *(bf16x8*)&Vs[row * 128 + sblk * 8] =
                *(const bf16x8*)&vg[(size_t)row * 4096 + k0];
        }
        __syncthreads();

        // S = q * K^T  (this wave's 16 q-rows x 128 kv)
        f32x4 s[8];
#pragma unroll
        for (int t = 0; t < 8; t++) {
            f32x4 a = fz;
#pragma unroll
            for (int c = 0; c < 4; c++) {
                bf16x8 kf = *(const bf16x8*)&Ks[(t * 16 + lrow) * 128 + c * 32 + quad * 8];
                a = MFMA16(qf[c], kf, a);
            }
            s[t] = a;
        }
#pragma unroll
        for (int t = 0; t < 8; t++) s[t] = s[t] * scale;

        // online softmax; s[t][r] = S[q-row=quad*4+r][kv=t*16+lrow]
        float alpha[4];
#pragma unroll
        for (int r = 0; r < 4; r++) {
            float mx = s[0][r];
#pragma unroll
            for (int t = 1; t < 8; t++) mx = fmaxf(mx, s[t][r]);
#pragma unroll
            for (int off = 1; off < 16; off <<= 1) mx = fmaxf(mx, __shfl_xor(mx, off));
            const float mn = fmaxf(mrow[r], mx);
            alpha[r] = __expf(mrow[r] - mn);
            mrow[r] = mn;
            float sum = 0.f;
#pragma unroll
            for (int t = 0; t < 8; t++) {
                float p = __expf(s[t][r] - mn);
                s[t][r] = p;
                sum += p;
            }
#pragma unroll
            for (int off = 1; off < 16; off <<= 1) sum += __shfl_xor(sum, off);
            lsum[r] = lsum[r] * alpha[r] + sum;
        }

        // P (C-layout) -> LDS -> A-layout frags
        u16* Pw = &Ps[wave][0];
#pragma unroll
        for (int t = 0; t < 8; t++)
#pragma unroll
            for (int r = 0; r < 4; r++)
                Pw[(quad * 4 + r) * 136 + t * 16 + lrow] = f2bf(s[t][r]);
        __syncthreads();
        bf16x8 pf[4];
#pragma unroll
        for (int c = 0; c < 4; c++)
            pf[c] = *(const bf16x8*)&Pw[lrow * 136 + c * 32 + quad * 8];

        // O = O*alpha + P*V
        const f32x4 av = {alpha[0], alpha[1], alpha[2], alpha[3]};
#pragma unroll
        for (int n = 0; n < 8; n++) {
            f32x4 o = oacc[n] * av;
#pragma unroll
            for (int c = 0; c < 4; c++) {
                bf16x8 vf = *(const bf16x8*)&Vs[(n * 16 + lrow) * 128 + c * 32 + quad * 8];
                o = MFMA16(pf[c], vf, o);
            }
            oacc[n] = o;
        }
    }

    const f32x4 inv = {1.f / lsum[0], 1.f / lsum[1], 1.f / lsum[2], 1.f / lsum[3]};
#pragma unroll
    for (int n = 0; n < 8; n++) {
        f32x4 o = oacc[n] * inv;
#pragma unroll
        for (int r = 0; r < 4; r++) {
            const size_t row = (size_t)(b * 512 + q0 + wave * 16 + quad * 4 + r);
            ob[((row * 8 + h) << 7) + n * 16 + lrow] = f2bf(o[r]);
        }
    }
}

// ---------------------------------------------------------------------------
extern "C" void kernel_launch(void* const* d_in, const int* in_sizes, int n_in,
                              void* d_out, int out_size, void* d_ws, size_t ws_size,
                              hipStream_t stream) {
    const float* inq   = (const float*)d_in[0];  // (4,512,1024)   f32
    const float* inkv  = (const float*)d_in[1];  // (4,4096,1024)  f32
    const float* Wq    = (const float*)d_in[2];  // (1024,1024)    f32
    const float* Wkv   = (const float*)d_in[3];  // (1024,2048)    f32
    const float* Wproj = (const float*)d_in[4];  // (1024,1024)    f32 [he x o]
    const float* bproj = (const float*)d_in[5];  // (1024,)        f32
    float* out = (float*)d_out;                  // (4,512,1024)   f32

    u16* WqT    = (u16*)d_ws;                          // 1M elems
    u16* WkvT   = WqT + (size_t)1024 * 1024;           // 2M
    u16* WprojT = WkvT + (size_t)2048 * 1024;          // 1M
    u16* Aq     = WprojT + (size_t)1024 * 1024;        // 2M   bf16(inputs_q)
    u16* Akv    = Aq + (size_t)2048 * 1024;            // 16M  bf16(inputs_kv)
    u16* qbuf   = Akv + (size_t)16384 * 1024;          // 2M   (B,Q,H,DH)
    u16* kvbuf  = qbuf + (size_t)2048 * 1024;          // 32M  (B,K,H,2DH)
    u16* vTbuf  = kvbuf + (size_t)16384 * 2048;        // 16M  (B,H,DH,K)
    u16* obuf   = vTbuf + (size_t)32 * 128 * 4096;     // 2M   (B,Q,H,DH)

    // 1) input converts + weight transposes (f32 -> bf16)
    convert_f32_bf16<<<1024, 256, 0, stream>>>(inq, Aq, 262144);
    convert_f32_bf16<<<8192, 256, 0, stream>>>(inkv, Akv, 2097152);
    transpose_f32_bf16<<<dim3(16, 16), 256, 0, stream>>>(Wq, WqT, 1024, 1024);
    transpose_f32_bf16<<<dim3(32, 16), 256, 0, stream>>>(Wkv, WkvT, 1024, 2048);
    transpose_f32_bf16<<<dim3(16, 16), 256, 0, stream>>>(Wproj, WprojT, 1024, 1024);

    // 2) projections (bf16 out)
    gemm_bt<false><<<16 * 8, 256, 0, stream>>>(Aq, WqT, qbuf, nullptr, 2048, 1024, 1024);
    gemm_bt<false><<<128 * 16, 256, 0, stream>>>(Akv, WkvT, kvbuf, nullptr, 16384, 2048, 1024);

    // 3) V transpose
    transpose_v<<<2048, 256, 0, stream>>>(kvbuf, vTbuf);

    // 4) flash attention
    flash_attn<<<256, 256, 0, stream>>>(qbuf, kvbuf, vTbuf, obuf);

    // 5) output projection + bias (f32 out)
    gemm_bt<true><<<16 * 8, 256, 0, stream>>>(obuf, WprojT, (void*)out, bproj, 2048, 1024, 1024);
}

// Round 4
// 450.242 us; speedup vs baseline: 1.1208x; 1.1208x over previous
//
#include <hip/hip_runtime.h>
#include <hip/hip_bf16.h>
#include <cstdint>

typedef unsigned short u16;
typedef unsigned int u32;
typedef __bf16 bf16x8 __attribute__((ext_vector_type(8)));
typedef u16 u16x8 __attribute__((ext_vector_type(8)));
typedef float f32x4 __attribute__((ext_vector_type(4)));

#define MFMA16(a, b, c) __builtin_amdgcn_mfma_f32_16x16x32_bf16(a, b, c, 0, 0, 0)

__device__ __forceinline__ u16 f2bf(float f) {
    u32 u; __builtin_memcpy(&u, &f, 4);
    u = u + 0x7fffu + ((u >> 16) & 1u);
    return (u16)(u >> 16);
}

// ---------------------------------------------------------------------------
// f32 -> bf16 convert, 8 elems/thread.
// ---------------------------------------------------------------------------
__global__ __launch_bounds__(256) void convert_f32_bf16(const float* __restrict__ in,
                                                        u16* __restrict__ out, int n8) {
    const int i = blockIdx.x * 256 + threadIdx.x;
    if (i >= n8) return;
    const float4* p = (const float4*)in + (size_t)i * 2;
    const float4 a = p[0], b = p[1];
    u16x8 v;
    v[0] = f2bf(a.x); v[1] = f2bf(a.y); v[2] = f2bf(a.z); v[3] = f2bf(a.w);
    v[4] = f2bf(b.x); v[5] = f2bf(b.y); v[6] = f2bf(b.z); v[7] = f2bf(b.w);
    ((u16x8*)out)[i] = v;
}

// ---------------------------------------------------------------------------
// f32 (R x C) row-major -> bf16 (C x R) row-major transpose.
// ---------------------------------------------------------------------------
__global__ __launch_bounds__(256) void transpose_f32_bf16(const float* __restrict__ in,
                                                          u16* __restrict__ out,
                                                          int R, int C) {
    __shared__ u16 t[64][65];
    const int r0 = blockIdx.y << 6, c0 = blockIdx.x << 6;
    const int tid = threadIdx.x;
#pragma unroll
    for (int i = 0; i < 16; i++) {
        int idx = i * 256 + tid;
        int r = idx >> 6, c = idx & 63;
        t[r][c] = f2bf(in[(size_t)(r0 + r) * C + c0 + c]);
    }
    __syncthreads();
#pragma unroll
    for (int i = 0; i < 16; i++) {
        int idx = i * 256 + tid;
        int c = idx >> 6, r = idx & 63;
        out[(size_t)(c0 + c) * R + r0 + r] = t[r][c];
    }
}

// ---------------------------------------------------------------------------
// V transpose: kv (B,K,H,256)[e>=128] -> vT (B,H,128,K)
// ---------------------------------------------------------------------------
__global__ __launch_bounds__(256) void transpose_v(const u16* __restrict__ kv,
                                                   u16* __restrict__ vT) {
    __shared__ u16 t[64][130];
    const int blk = blockIdx.x;
    const int kt = blk & 63, h = (blk >> 6) & 7, b = blk >> 9;
    const int k0 = kt * 64, tid = threadIdx.x;
    const u16* src = kv + ((size_t)(b * 4096 + k0) * 8 + h) * 256 + 128;
#pragma unroll
    for (int i = 0; i < 16; i++) {
        int idx = i * 256 + tid;
        int ki = idx >> 6, e2 = (idx & 63) << 1;
        u32 v = *(const u32*)(src + (size_t)ki * 2048 + e2);
        t[ki][e2] = (u16)v; t[ki][e2 + 1] = (u16)(v >> 16);
    }
    __syncthreads();
    u16* dst = vT + ((size_t)(b * 8 + h)) * 128 * 4096 + k0;
#pragma unroll
    for (int i = 0; i < 16; i++) {
        int idx = i * 256 + tid;
        int e = idx >> 5, ki2 = (idx & 31) << 1;
        u32 v = (u32)t[ki2][e] | ((u32)t[ki2 + 1][e] << 16);
        *(u32*)(dst + (size_t)e * 4096 + ki2) = v;
    }
}

// ---------------------------------------------------------------------------
// GEMM: C(MxN) = A(MxK) * B^T(NxK). LDS rows padded to 72 elems (36 dwords,
// 36%32=4 -> row advances bank by 4 -> balanced 8 dwords/bank, was 16-way).
// ---------------------------------------------------------------------------
template <bool OUTF32>
__global__ __launch_bounds__(256) void gemm_bt(const u16* __restrict__ A,
                                               const u16* __restrict__ B,
                                               void* __restrict__ Cv,
                                               const float* __restrict__ bias,
                                               int M, int N, int K) {
    __shared__ __align__(16) u16 As[128 * 72];
    __shared__ __align__(16) u16 Bs[128 * 72];
    const int tid = threadIdx.x;
    const int wave = tid >> 6, lane = tid & 63;
    const int lrow = lane & 15, quad = lane >> 4;
    const int nb = N >> 7;
    const int bx = blockIdx.x % nb, by = blockIdx.x / nb;
    const long m0 = (long)by << 7, n0 = (long)bx << 7;
    const int wm = (wave >> 1) << 6, wn = (wave & 1) << 6;

    const f32x4 fz = {0.f, 0.f, 0.f, 0.f};
    f32x4 acc[4][4];
#pragma unroll
    for (int i = 0; i < 4; i++)
#pragma unroll
        for (int j = 0; j < 4; j++) acc[i][j] = fz;

    const int srow = tid >> 3;        // [0,32)
    const int sblk = tid & 7;         // [0,8)

    for (int k0 = 0; k0 < K; k0 += 64) {
        __syncthreads();
#pragma unroll
        for (int i = 0; i < 4; i++) {
            const int row = i * 32 + srow;
            *(bf16x8*)&As[row * 72 + sblk * 8] =
                *(const bf16x8*)&A[(m0 + row) * K + k0 + sblk * 8];
            *(bf16x8*)&Bs[row * 72 + sblk * 8] =
                *(const bf16x8*)&B[(n0 + row) * K + k0 + sblk * 8];
        }
        __syncthreads();
#pragma unroll
        for (int c = 0; c < 2; c++) {
            const int ko = c * 32 + quad * 8;
            bf16x8 af[4], bfr[4];
#pragma unroll
            for (int i = 0; i < 4; i++) {
                af[i]  = *(const bf16x8*)&As[(wm + i * 16 + lrow) * 72 + ko];
                bfr[i] = *(const bf16x8*)&Bs[(wn + i * 16 + lrow) * 72 + ko];
            }
#pragma unroll
            for (int i = 0; i < 4; i++)
#pragma unroll
                for (int j = 0; j < 4; j++)
                    acc[i][j] = MFMA16(af[i], bfr[j], acc[i][j]);
        }
    }
#pragma unroll
    for (int j = 0; j < 4; j++) {
        const long col = n0 + wn + j * 16 + lrow;
        const float bv = bias ? bias[col] : 0.0f;
#pragma unroll
        for (int i = 0; i < 4; i++) {
            const long row = m0 + wm + i * 16 + quad * 4;
#pragma unroll
            for (int r = 0; r < 4; r++) {
                const float v = acc[i][j][r] + bv;
                if (OUTF32) ((float*)Cv)[(row + r) * N + col] = v;
                else        ((u16*)Cv)[(row + r) * N + col] = f2bf(v);
            }
        }
    }
}

// ---------------------------------------------------------------------------
// Split-K flash attention. grid = B*H*(Q/64)*4 = 1024 blocks; block handles
// kv range [split*1024, split*1024+1024) with K-tile 64. Writes unnormalized
// partial O (fp32) + running m,l per q-row. LDS ~45 KB -> 3 blocks/CU.
// blk = (((b*8+h)*8)+qt)*4 + split
// ---------------------------------------------------------------------------
__global__ __launch_bounds__(256) void flash_attn_split(const u16* __restrict__ qb,
                                                        const u16* __restrict__ kvb,
                                                        const u16* __restrict__ vTb,
                                                        float* __restrict__ Opart,
                                                        float* __restrict__ Mpart,
                                                        float* __restrict__ Lpart) {
    __shared__ __align__(16) u16 Ks[64 * 136];    // kv-pos x head-dim, pad 136
    __shared__ __align__(16) u16 Vs[128 * 72];    // head-dim x kv-local, pad 72
    __shared__ __align__(16) u16 Ps[4][16 * 72];  // per-wave P, pad 72
    const int tid = threadIdx.x, wave = tid >> 6, lane = tid & 63;
    const int lrow = lane & 15, quad = lane >> 4;
    const int blk = blockIdx.x;
    const int split = blk & 3, qt = (blk >> 2) & 7, h = (blk >> 5) & 7, b = blk >> 8;
    const int q0 = qt * 64;
    const int kbase = split * 1024;

    bf16x8 qf[4];
    {
        const u16* qp = qb + (((size_t)(b * 512 + q0 + wave * 16 + lrow) * 8 + h) << 7) + quad * 8;
#pragma unroll
        for (int c = 0; c < 4; c++) qf[c] = *(const bf16x8*)(qp + c * 32);
    }

    const f32x4 fz = {0.f, 0.f, 0.f, 0.f};
    f32x4 oacc[8];
#pragma unroll
    for (int n = 0; n < 8; n++) oacc[n] = fz;
    float mrow[4] = {-1e30f, -1e30f, -1e30f, -1e30f};
    float lsum[4] = {0.f, 0.f, 0.f, 0.f};
    const float scale = 0.08838834764831845f;  // 1/sqrt(128)

    const int srowK = tid >> 4, sblkK = tid & 15;   // K: 16 rows x 16 blocks / round
    const int srowV = tid >> 3, sblkV = tid & 7;    // V: 32 rows x 8 blocks / round
    const u16* kg = kvb + (size_t)b * 4096 * 2048 + h * 256 + sblkK * 8;
    const u16* vg = vTb + (size_t)(b * 8 + h) * 128 * 4096 + sblkV * 8;

    for (int k0 = kbase; k0 < kbase + 1024; k0 += 64) {
        __syncthreads();
#pragma unroll
        for (int i = 0; i < 4; i++) {
            const int rK = i * 16 + srowK;
            *(bf16x8*)&Ks[rK * 136 + sblkK * 8] =
                *(const bf16x8*)&kg[(size_t)(k0 + rK) * 2048];
            const int rV = i * 32 + srowV;
            *(bf16x8*)&Vs[rV * 72 + sblkV * 8] =
                *(const bf16x8*)&vg[(size_t)rV * 4096 + k0];
        }
        __syncthreads();

        // S = q * K^T (16 q-rows x 64 kv)
        f32x4 s[4];
#pragma unroll
        for (int t = 0; t < 4; t++) {
            f32x4 a = fz;
#pragma unroll
            for (int c = 0; c < 4; c++) {
                bf16x8 kf = *(const bf16x8*)&Ks[(t * 16 + lrow) * 136 + c * 32 + quad * 8];
                a = MFMA16(qf[c], kf, a);
            }
            s[t] = a * scale;
        }

        // online softmax; s[t][r] = S[q-row=quad*4+r][kv=t*16+lrow]
        float alpha[4];
#pragma unroll
        for (int r = 0; r < 4; r++) {
            float mx = fmaxf(fmaxf(s[0][r], s[1][r]), fmaxf(s[2][r], s[3][r]));
#pragma unroll
            for (int off = 1; off < 16; off <<= 1) mx = fmaxf(mx, __shfl_xor(mx, off));
            const float mn = fmaxf(mrow[r], mx);
            alpha[r] = __expf(mrow[r] - mn);
            mrow[r] = mn;
            float sum = 0.f;
#pragma unroll
            for (int t = 0; t < 4; t++) {
                float p = __expf(s[t][r] - mn);
                s[t][r] = p;
                sum += p;
            }
#pragma unroll
            for (int off = 1; off < 16; off <<= 1) sum += __shfl_xor(sum, off);
            lsum[r] = lsum[r] * alpha[r] + sum;
        }

        // P (C-layout) -> wave-private LDS -> A-layout frags
        u16* Pw = &Ps[wave][0];
#pragma unroll
        for (int t = 0; t < 4; t++)
#pragma unroll
            for (int r = 0; r < 4; r++)
                Pw[(quad * 4 + r) * 72 + t * 16 + lrow] = f2bf(s[t][r]);
        asm volatile("s_waitcnt lgkmcnt(0)" ::: "memory");
        bf16x8 pf0 = *(const bf16x8*)&Pw[lrow * 72 + quad * 8];
        bf16x8 pf1 = *(const bf16x8*)&Pw[lrow * 72 + 32 + quad * 8];

        // O = O*alpha + P*V
        const f32x4 av = {alpha[0], alpha[1], alpha[2], alpha[3]};
#pragma unroll
        for (int n = 0; n < 8; n++) {
            f32x4 o = oacc[n] * av;
            o = MFMA16(pf0, *(const bf16x8*)&Vs[(n * 16 + lrow) * 72 + quad * 8], o);
            o = MFMA16(pf1, *(const bf16x8*)&Vs[(n * 16 + lrow) * 72 + 32 + quad * 8], o);
            oacc[n] = o;
        }
    }

    // write unnormalized partials
    float* Ob = Opart + (size_t)blk * 8192;
#pragma unroll
    for (int n = 0; n < 8; n++)
#pragma unroll
        for (int r = 0; r < 4; r++)
            Ob[(wave * 16 + quad * 4 + r) * 128 + n * 16 + lrow] = oacc[n][r];
    if (lrow == 0) {
#pragma unroll
        for (int r = 0; r < 4; r++) {
            const int row = blk * 64 + wave * 16 + quad * 4 + r;
            Mpart[row] = mrow[r];
            Lpart[row] = lsum[r];
        }
    }
}

// ---------------------------------------------------------------------------
// Combine 4 split partials -> obuf (B,Q,H,128) bf16.
// grid 256 (= (b*8+h)*8+qt), 256 threads: 64 rows x 4 col-groups of 32.
// ---------------------------------------------------------------------------
__global__ __launch_bounds__(256) void combine_attn(const float* __restrict__ Opart,
                                                    const float* __restrict__ Mpart,
                                                    const float* __restrict__ Lpart,
                                                    u16* __restrict__ ob) {
    const int c = blockIdx.x;
    const int qt = c & 7, h = (c >> 3) & 7, b = c >> 6;
    const int lr = threadIdx.x >> 2, cg = (threadIdx.x & 3) * 32;
    float ms[4], w[4];
    float m = -1e30f;
#pragma unroll
    for (int s = 0; s < 4; s++) { ms[s] = Mpart[(c * 4 + s) * 64 + lr]; m = fmaxf(m, ms[s]); }
    float l = 0.f;
#pragma unroll
    for (int s = 0; s < 4; s++) { w[s] = __expf(ms[s] - m); l += w[s] * Lpart[(c * 4 + s) * 64 + lr]; }
    const float inv = 1.f / l;
#pragma unroll
    for (int s = 0; s < 4; s++) w[s] *= inv;
    const size_t orow = ((size_t)(b * 512 + qt * 64 + lr) * 8 + h) << 7;
#pragma unroll
    for (int j = 0; j < 4; j++) {
        f32x4 a0 = {0.f, 0.f, 0.f, 0.f}, a1 = a0;
#pragma unroll
        for (int s = 0; s < 4; s++) {
            const f32x4* p = (const f32x4*)(Opart + ((size_t)(c * 4 + s)) * 8192 + lr * 128 + cg + j * 8);
            a0 += p[0] * w[s];
            a1 += p[1] * w[s];
        }
        u16x8 v;
#pragma unroll
        for (int i = 0; i < 4; i++) { v[i] = f2bf(a0[i]); v[4 + i] = f2bf(a1[i]); }
        *(u16x8*)&ob[orow + cg + j * 8] = v;
    }
}

// ---------------------------------------------------------------------------
extern "C" void kernel_launch(void* const* d_in, const int* in_sizes, int n_in,
                              void* d_out, int out_size, void* d_ws, size_t ws_size,
                              hipStream_t stream) {
    const float* inq   = (const float*)d_in[0];
    const float* inkv  = (const float*)d_in[1];
    const float* Wq    = (const float*)d_in[2];
    const float* Wkv   = (const float*)d_in[3];
    const float* Wproj = (const float*)d_in[4];
    const float* bproj = (const float*)d_in[5];
    float* out = (float*)d_out;

    u16* WqT    = (u16*)d_ws;                          // 1M elems
    u16* WkvT   = WqT + (size_t)1024 * 1024;           // 2M
    u16* WprojT = WkvT + (size_t)2048 * 1024;          // 1M
    u16* Aq     = WprojT + (size_t)1024 * 1024;        // 2M   bf16(inputs_q); dead after q-gemm
    u16* Akv    = Aq + (size_t)2048 * 1024;            // 16M  bf16(inputs_kv); dead after kv-gemm
    u16* qbuf   = Akv + (size_t)16384 * 1024;          // 2M   (B,Q,H,DH)
    u16* kvbuf  = qbuf + (size_t)2048 * 1024;          // 32M  (B,K,H,2DH)
    u16* vTbuf  = kvbuf + (size_t)16384 * 2048;        // 16M  (B,H,DH,K)
    u16* obuf   = vTbuf + (size_t)32 * 128 * 4096;     // 2M   (B,Q,H,DH)

    // flash partials alias dead input-convert regions
    float* Opart = (float*)Akv;                        // 1024*8192 f32 = 32 MB
    float* Mpart = (float*)Aq;                         // 64K f32
    float* Lpart = Mpart + 65536;                      // 64K f32

    convert_f32_bf16<<<1024, 256, 0, stream>>>(inq, Aq, 262144);
    convert_f32_bf16<<<8192, 256, 0, stream>>>(inkv, Akv, 2097152);
    transpose_f32_bf16<<<dim3(16, 16), 256, 0, stream>>>(Wq, WqT, 1024, 1024);
    transpose_f32_bf16<<<dim3(32, 16), 256, 0, stream>>>(Wkv, WkvT, 1024, 2048);
    transpose_f32_bf16<<<dim3(16, 16), 256, 0, stream>>>(Wproj, WprojT, 1024, 1024);

    gemm_bt<false><<<16 * 8, 256, 0, stream>>>(Aq, WqT, qbuf, nullptr, 2048, 1024, 1024);
    gemm_bt<false><<<128 * 16, 256, 0, stream>>>(Akv, WkvT, kvbuf, nullptr, 16384, 2048, 1024);

    transpose_v<<<2048, 256, 0, stream>>>(kvbuf, vTbuf);

    flash_attn_split<<<1024, 256, 0, stream>>>(qbuf, kvbuf, vTbuf, Opart, Mpart, Lpart);
    combine_attn<<<256, 256, 0, stream>>>(Opart, Mpart, Lpart, obuf);

    gemm_bt<true><<<16 * 8, 256, 0, stream>>>(obuf, WprojT, (void*)out, bproj, 2048, 1024, 1024);
}

// Round 6
// 336.037 us; speedup vs baseline: 1.5017x; 1.3399x over previous
//
#include <hip/hip_runtime.h>
#include <hip/hip_bf16.h>
#include <cstdint>

typedef unsigned short u16;
typedef unsigned int u32;
typedef __bf16 bf16x8 __attribute__((ext_vector_type(8)));
typedef u16 u16x8 __attribute__((ext_vector_type(8)));
typedef u16 u16x4 __attribute__((ext_vector_type(4)));
typedef float f32x4 __attribute__((ext_vector_type(4)));

#define MFMA16(a, b, c) __builtin_amdgcn_mfma_f32_16x16x32_bf16(a, b, c, 0, 0, 0)

__device__ __forceinline__ u16 f2bf(float f) {
    u32 u; __builtin_memcpy(&u, &f, 4);
    u = u + 0x7fffu + ((u >> 16) & 1u);
    return (u16)(u >> 16);
}

// ---------------------------------------------------------------------------
// f32 -> bf16 convert, 8 elems/thread.
// ---------------------------------------------------------------------------
__global__ __launch_bounds__(256) void convert_f32_bf16(const float* __restrict__ in,
                                                        u16* __restrict__ out, int n8) {
    const int i = blockIdx.x * 256 + threadIdx.x;
    if (i >= n8) return;
    const float4* p = (const float4*)in + (size_t)i * 2;
    const float4 a = p[0], b = p[1];
    u16x8 v;
    v[0] = f2bf(a.x); v[1] = f2bf(a.y); v[2] = f2bf(a.z); v[3] = f2bf(a.w);
    v[4] = f2bf(b.x); v[5] = f2bf(b.y); v[6] = f2bf(b.z); v[7] = f2bf(b.w);
    ((u16x8*)out)[i] = v;
}

// ---------------------------------------------------------------------------
// f32 (R x C) row-major -> bf16 (C x R) row-major transpose.
// ---------------------------------------------------------------------------
__global__ __launch_bounds__(256) void transpose_f32_bf16(const float* __restrict__ in,
                                                          u16* __restrict__ out,
                                                          int R, int C) {
    __shared__ u16 t[64][65];
    const int r0 = blockIdx.y << 6, c0 = blockIdx.x << 6;
    const int tid = threadIdx.x;
#pragma unroll
    for (int i = 0; i < 16; i++) {
        int idx = i * 256 + tid;
        int r = idx >> 6, c = idx & 63;
        t[r][c] = f2bf(in[(size_t)(r0 + r) * C + c0 + c]);
    }
    __syncthreads();
#pragma unroll
    for (int i = 0; i < 16; i++) {
        int idx = i * 256 + tid;
        int c = idx >> 6, r = idx & 63;
        out[(size_t)(c0 + c) * R + r0 + r] = t[r][c];
    }
}

// ---------------------------------------------------------------------------
// V transpose: kv (B,K,H,256)[e>=128] -> vT (B,H,128,K)
// ---------------------------------------------------------------------------
__global__ __launch_bounds__(256) void transpose_v(const u16* __restrict__ kv,
                                                   u16* __restrict__ vT) {
    __shared__ u16 t[64][130];
    const int blk = blockIdx.x;
    const int kt = blk & 63, h = (blk >> 6) & 7, b = blk >> 9;
    const int k0 = kt * 64, tid = threadIdx.x;
    const u16* src = kv + ((size_t)(b * 4096 + k0) * 8 + h) * 256 + 128;
#pragma unroll
    for (int i = 0; i < 16; i++) {
        int idx = i * 256 + tid;
        int ki = idx >> 6, e2 = (idx & 63) << 1;
        u32 v = *(const u32*)(src + (size_t)ki * 2048 + e2);
        t[ki][e2] = (u16)v; t[ki][e2 + 1] = (u16)(v >> 16);
    }
    __syncthreads();
    u16* dst = vT + ((size_t)(b * 8 + h)) * 128 * 4096 + k0;
#pragma unroll
    for (int i = 0; i < 16; i++) {
        int idx = i * 256 + tid;
        int e = idx >> 5, ki2 = (idx & 31) << 1;
        u32 v = (u32)t[ki2][e] | ((u32)t[ki2 + 1][e] << 16);
        *(u32*)(dst + (size_t)e * 4096 + ki2) = v;
    }
}

// ---------------------------------------------------------------------------
// GEMM: C(MxN) = A(MxK) * B^T(NxK). LDS rows padded to 72 elems.
// ---------------------------------------------------------------------------
template <bool OUTF32>
__global__ __launch_bounds__(256) void gemm_bt(const u16* __restrict__ A,
                                               const u16* __restrict__ B,
                                               void* __restrict__ Cv,
                                               const float* __restrict__ bias,
                                               int M, int N, int K) {
    __shared__ __align__(16) u16 As[128 * 72];
    __shared__ __align__(16) u16 Bs[128 * 72];
    const int tid = threadIdx.x;
    const int wave = tid >> 6, lane = tid & 63;
    const int lrow = lane & 15, quad = lane >> 4;
    const int nb = N >> 7;
    const int bx = blockIdx.x % nb, by = blockIdx.x / nb;
    const long m0 = (long)by << 7, n0 = (long)bx << 7;
    const int wm = (wave >> 1) << 6, wn = (wave & 1) << 6;

    const f32x4 fz = {0.f, 0.f, 0.f, 0.f};
    f32x4 acc[4][4];
#pragma unroll
    for (int i = 0; i < 4; i++)
#pragma unroll
        for (int j = 0; j < 4; j++) acc[i][j] = fz;

    const int srow = tid >> 3;        // [0,32)
    const int sblk = tid & 7;         // [0,8)

    for (int k0 = 0; k0 < K; k0 += 64) {
        __syncthreads();
#pragma unroll
        for (int i = 0; i < 4; i++) {
            const int row = i * 32 + srow;
            *(bf16x8*)&As[row * 72 + sblk * 8] =
                *(const bf16x8*)&A[(m0 + row) * K + k0 + sblk * 8];
            *(bf16x8*)&Bs[row * 72 + sblk * 8] =
                *(const bf16x8*)&B[(n0 + row) * K + k0 + sblk * 8];
        }
        __syncthreads();
#pragma unroll
        for (int c = 0; c < 2; c++) {
            const int ko = c * 32 + quad * 8;
            bf16x8 af[4], bfr[4];
#pragma unroll
            for (int i = 0; i < 4; i++) {
                af[i]  = *(const bf16x8*)&As[(wm + i * 16 + lrow) * 72 + ko];
                bfr[i] = *(const bf16x8*)&Bs[(wn + i * 16 + lrow) * 72 + ko];
            }
#pragma unroll
            for (int i = 0; i < 4; i++)
#pragma unroll
                for (int j = 0; j < 4; j++)
                    acc[i][j] = MFMA16(af[i], bfr[j], acc[i][j]);
        }
    }
#pragma unroll
    for (int j = 0; j < 4; j++) {
        const long col = n0 + wn + j * 16 + lrow;
        const float bv = bias ? bias[col] : 0.0f;
#pragma unroll
        for (int i = 0; i < 4; i++) {
            const long row = m0 + wm + i * 16 + quad * 4;
#pragma unroll
            for (int r = 0; r < 4; r++) {
                const float v = acc[i][j][r] + bv;
                if (OUTF32) ((float*)Cv)[(row + r) * N + col] = v;
                else        ((u16*)Cv)[(row + r) * N + col] = f2bf(v);
            }
        }
    }
}

// ---------------------------------------------------------------------------
// Split-K flash attention, transposed-MFMA dataflow, XOR-swizzled LDS
// (zero padding). 512 threads = 8 waves, q-tile 128 (wave w: rows w*16..+15),
// kv-tile 64, 4 splits of 1024 kv.
// LDS: Ks 64x128, Vs 128x64, Ps 8x(16x64) = 49152 B -> >=2 blocks/CU,
// grid 512 = exactly 2/CU resident, no tail.
// blk = (((b*8+h)*4)+qt)*4 + split
// ---------------------------------------------------------------------------
__global__ __launch_bounds__(512) void flash_attn_split(const u16* __restrict__ qb,
                                                        const u16* __restrict__ kvb,
                                                        const u16* __restrict__ vTb,
                                                        float* __restrict__ Opart,
                                                        float* __restrict__ Mpart,
                                                        float* __restrict__ Lpart) {
    __shared__ __align__(16) u16 Ks[64 * 128];    // [kv][dh], blk^(kv&15) swizzle
    __shared__ __align__(16) u16 Vs[128 * 64];    // [dh][kv], blk^(dh&7) swizzle
    __shared__ __align__(16) u16 Ps[8][16 * 64];  // per-wave [q][kv], blk^(q&7)
    const int tid = threadIdx.x, wave = tid >> 6, lane = tid & 63;
    const int lrow = lane & 15, quad = lane >> 4;
    const int blk = blockIdx.x;
    const int split = blk & 3, qt = (blk >> 2) & 3, h = (blk >> 4) & 7, b = blk >> 7;
    const int q0 = qt * 128;
    const int kbase = split * 1024;

    // Q B-frags: B[n=q=lrow][k=dh=quad*8+c*32+j]
    bf16x8 qf[4];
    {
        const u16* qp = qb + (((size_t)(b * 512 + q0 + wave * 16 + lrow) * 8 + h) << 7) + quad * 8;
#pragma unroll
        for (int c = 0; c < 4; c++) qf[c] = *(const bf16x8*)(qp + c * 32);
    }

    const f32x4 fz = {0.f, 0.f, 0.f, 0.f};
    f32x4 oacc[8];           // O^T: oacc[g][r] = O[dh=g*16+quad*4+r][q=lrow]
#pragma unroll
    for (int g = 0; g < 8; g++) oacc[g] = fz;
    float mrow = -1e30f, lsum = 0.f;   // per-lane, q=lrow (replicated across quads)
    const float scale = 0.08838834764831845f;  // 1/sqrt(128)

    // staging: K 64 rows x 16 blks (1024 chunks), V 128 rows x 8 blks (1024)
    const int kRow = tid >> 4, kBlk = tid & 15;   // kRow 0..31, rows kRow, kRow+32
    const int vRow = tid >> 3, vBlk = tid & 7;    // vRow 0..63, rows vRow, vRow+64
    const u16* kg = kvb + (size_t)b * 4096 * 2048 + h * 256 + kBlk * 8;
    const u16* vg = vTb + (size_t)(b * 8 + h) * 128 * 4096 + vBlk * 8;

    for (int k0 = kbase; k0 < kbase + 1024; k0 += 64) {
        __syncthreads();
#pragma unroll
        for (int i = 0; i < 2; i++) {
            const int r = i * 32 + kRow;
            *(bf16x8*)&Ks[r * 128 + ((kBlk ^ (r & 15)) << 3)] =
                *(const bf16x8*)&kg[(size_t)(k0 + r) * 2048];
            const int rv = i * 64 + vRow;
            *(bf16x8*)&Vs[rv * 64 + ((vBlk ^ (rv & 7)) << 3)] =
                *(const bf16x8*)&vg[(size_t)rv * 4096 + k0];
        }
        __syncthreads();

        // S^T: s[t][r] = S[q=lrow][kv = t*16 + quad*4 + r]
        f32x4 s[4];
#pragma unroll
        for (int t = 0; t < 4; t++) {
            f32x4 a = fz;
#pragma unroll
            for (int c = 0; c < 4; c++) {
                const bf16x8 kf = *(const bf16x8*)
                    &Ks[(t * 16 + lrow) * 128 + (((c * 4 + quad) ^ lrow) << 3)];
                a = MFMA16(kf, qf[c], a);
            }
            s[t] = a * scale;
        }

        // per-lane online softmax over 64 kv (16 in-lane + 2 cross-quad shfl)
        float mx = s[0][0];
#pragma unroll
        for (int t = 0; t < 4; t++)
#pragma unroll
            for (int r = 0; r < 4; r++) mx = fmaxf(mx, s[t][r]);
        mx = fmaxf(mx, __shfl_xor(mx, 16));
        mx = fmaxf(mx, __shfl_xor(mx, 32));
        const float mn = fmaxf(mrow, mx);
        const float alpha = __expf(mrow - mn);
        mrow = mn;
        float sum = 0.f;
#pragma unroll
        for (int t = 0; t < 4; t++)
#pragma unroll
            for (int r = 0; r < 4; r++) {
                float p = __expf(s[t][r] - mn);
                s[t][r] = p;
                sum += p;
            }
        sum += __shfl_xor(sum, 16);
        sum += __shfl_xor(sum, 32);
        lsum = lsum * alpha + sum;

        // P pack: lane holds P[q=lrow][kv=t*16+quad*4+r] -> b64 writes, swizzled
        u16* Pw = &Ps[wave][0];
#pragma unroll
        for (int t = 0; t < 4; t++) {
            u16x4 pk;
#pragma unroll
            for (int r = 0; r < 4; r++) pk[r] = f2bf(s[t][r]);
            const int kvo = t * 16 + quad * 4;
            *(u16x4*)&Pw[lrow * 64 + (((kvo >> 3) ^ (lrow & 7)) << 3) + (kvo & 7)] = pk;
        }
        asm volatile("s_waitcnt lgkmcnt(0)" ::: "memory");
        const bf16x8 pf0 = *(const bf16x8*)&Pw[lrow * 64 + ((quad ^ (lrow & 7)) << 3)];
        const bf16x8 pf1 = *(const bf16x8*)&Pw[lrow * 64 + (((4 + quad) ^ (lrow & 7)) << 3)];

        // O^T = O^T*alpha + MFMA(V^T-frag, P-frag)
#pragma unroll
        for (int g = 0; g < 8; g++) {
            f32x4 o = oacc[g] * alpha;
            o = MFMA16(*(const bf16x8*)&Vs[(g * 16 + lrow) * 64 + ((quad ^ (lrow & 7)) << 3)], pf0, o);
            o = MFMA16(*(const bf16x8*)&Vs[(g * 16 + lrow) * 64 + (((4 + quad) ^ (lrow & 7)) << 3)], pf1, o);
            oacc[g] = o;
        }
    }

    // unnormalized partials: Ob[q*128 + dh]
    float* Ob = Opart + (size_t)blk * 16384;
#pragma unroll
    for (int g = 0; g < 8; g++)
        *(f32x4*)&Ob[(wave * 16 + lrow) * 128 + g * 16 + quad * 4] = oacc[g];
    if (quad == 0) {
        const int row = blk * 128 + wave * 16 + lrow;
        Mpart[row] = mrow;
        Lpart[row] = lsum;
    }
}

// ---------------------------------------------------------------------------
// Combine 4 split partials -> obuf (B,Q,H,128) bf16.
// grid 128 (= (b*8+h)*4+qt), 512 threads: 128 rows x 4 col-groups of 32.
// ---------------------------------------------------------------------------
__global__ __launch_bounds__(512) void combine_attn(const float* __restrict__ Opart,
                                                    const float* __restrict__ Mpart,
                                                    const float* __restrict__ Lpart,
                                                    u16* __restrict__ ob) {
    const int c = blockIdx.x;
    const int qt = c & 3, h = (c >> 2) & 7, b = c >> 5;
    const int lr = threadIdx.x >> 2, cg = (threadIdx.x & 3) * 32;
    float ms[4], w[4];
    float m = -1e30f;
#pragma unroll
    for (int s = 0; s < 4; s++) { ms[s] = Mpart[(c * 4 + s) * 128 + lr]; m = fmaxf(m, ms[s]); }
    float l = 0.f;
#pragma unroll
    for (int s = 0; s < 4; s++) { w[s] = __expf(ms[s] - m); l += w[s] * Lpart[(c * 4 + s) * 128 + lr]; }
    const float inv = 1.f / l;
#pragma unroll
    for (int s = 0; s < 4; s++) w[s] *= inv;
    const size_t orow = ((size_t)(b * 512 + qt * 128 + lr) * 8 + h) << 7;
#pragma unroll
    for (int j = 0; j < 4; j++) {
        f32x4 a0 = {0.f, 0.f, 0.f, 0.f}, a1 = a0;
#pragma unroll
        for (int s = 0; s < 4; s++) {
            const f32x4* p = (const f32x4*)(Opart + ((size_t)(c * 4 + s)) * 16384 + (size_t)lr * 128 + cg + j * 8);
            a0 += p[0] * w[s];
            a1 += p[1] * w[s];
        }
        u16x8 v;
#pragma unroll
        for (int i = 0; i < 4; i++) { v[i] = f2bf(a0[i]); v[4 + i] = f2bf(a1[i]); }
        *(u16x8*)&ob[orow + cg + j * 8] = v;
    }
}

// ---------------------------------------------------------------------------
extern "C" void kernel_launch(void* const* d_in, const int* in_sizes, int n_in,
                              void* d_out, int out_size, void* d_ws, size_t ws_size,
                              hipStream_t stream) {
    const float* inq   = (const float*)d_in[0];
    const float* inkv  = (const float*)d_in[1];
    const float* Wq    = (const float*)d_in[2];
    const float* Wkv   = (const float*)d_in[3];
    const float* Wproj = (const float*)d_in[4];
    const float* bproj = (const float*)d_in[5];
    float* out = (float*)d_out;

    u16* WqT    = (u16*)d_ws;                          // 1M elems
    u16* WkvT   = WqT + (size_t)1024 * 1024;           // 2M
    u16* WprojT = WkvT + (size_t)2048 * 1024;          // 1M
    u16* Aq     = WprojT + (size_t)1024 * 1024;        // 2M   bf16(inputs_q); dead after q-gemm
    u16* Akv    = Aq + (size_t)2048 * 1024;            // 16M  bf16(inputs_kv); dead after kv-gemm
    u16* qbuf   = Akv + (size_t)16384 * 1024;          // 2M   (B,Q,H,DH)
    u16* kvbuf  = qbuf + (size_t)2048 * 1024;          // 32M  (B,K,H,2DH)
    u16* vTbuf  = kvbuf + (size_t)16384 * 2048;        // 16M  (B,H,DH,K)
    u16* obuf   = vTbuf + (size_t)32 * 128 * 4096;     // 2M   (B,Q,H,DH)

    // flash partials alias dead input-convert regions
    float* Opart = (float*)Akv;                        // 512*16384 f32 = 32 MB
    float* Mpart = (float*)Aq;                         // 64K f32
    float* Lpart = Mpart + 65536;                      // 64K f32

    convert_f32_bf16<<<1024, 256, 0, stream>>>(inq, Aq, 262144);
    convert_f32_bf16<<<8192, 256, 0, stream>>>(inkv, Akv, 2097152);
    transpose_f32_bf16<<<dim3(16, 16), 256, 0, stream>>>(Wq, WqT, 1024, 1024);
    transpose_f32_bf16<<<dim3(32, 16), 256, 0, stream>>>(Wkv, WkvT, 1024, 2048);
    transpose_f32_bf16<<<dim3(16, 16), 256, 0, stream>>>(Wproj, WprojT, 1024, 1024);

    gemm_bt<false><<<16 * 8, 256, 0, stream>>>(Aq, WqT, qbuf, nullptr, 2048, 1024, 1024);
    gemm_bt<false><<<128 * 16, 256, 0, stream>>>(Akv, WkvT, kvbuf, nullptr, 16384, 2048, 1024);

    transpose_v<<<2048, 256, 0, stream>>>(kvbuf, vTbuf);

    flash_attn_split<<<512, 512, 0, stream>>>(qbuf, kvbuf, vTbuf, Opart, Mpart, Lpart);
    combine_attn<<<128, 512, 0, stream>>>(Opart, Mpart, Lpart, obuf);

    gemm_bt<true><<<16 * 8, 256, 0, stream>>>(obuf, WprojT, (void*)out, bproj, 2048, 1024, 1024);
}

// Round 7
// 320.969 us; speedup vs baseline: 1.5722x; 1.0469x over previous
//
#include <hip/hip_runtime.h>
#include <hip/hip_bf16.h>
#include <cstdint>

typedef unsigned short u16;
typedef unsigned int u32;
typedef __bf16 bf16x8 __attribute__((ext_vector_type(8)));
typedef u16 u16x8 __attribute__((ext_vector_type(8)));
typedef u16 u16x4 __attribute__((ext_vector_type(4)));
typedef float f32x4 __attribute__((ext_vector_type(4)));

#define MFMA16(a, b, c) __builtin_amdgcn_mfma_f32_16x16x32_bf16(a, b, c, 0, 0, 0)

__device__ __forceinline__ void async16(const void* g, void* s) {
    __builtin_amdgcn_global_load_lds((const __attribute__((address_space(1))) void*)g,
                                     (__attribute__((address_space(3))) void*)s, 16, 0, 0);
}

__device__ __forceinline__ u16 f2bf(float f) {
    u32 u; __builtin_memcpy(&u, &f, 4);
    u = u + 0x7fffu + ((u >> 16) & 1u);
    return (u16)(u >> 16);
}

// ---------------------------------------------------------------------------
// f32 -> bf16 convert, 8 elems/thread.
// ---------------------------------------------------------------------------
__global__ __launch_bounds__(256) void convert_f32_bf16(const float* __restrict__ in,
                                                        u16* __restrict__ out, int n8) {
    const int i = blockIdx.x * 256 + threadIdx.x;
    if (i >= n8) return;
    const float4* p = (const float4*)in + (size_t)i * 2;
    const float4 a = p[0], b = p[1];
    u16x8 v;
    v[0] = f2bf(a.x); v[1] = f2bf(a.y); v[2] = f2bf(a.z); v[3] = f2bf(a.w);
    v[4] = f2bf(b.x); v[5] = f2bf(b.y); v[6] = f2bf(b.z); v[7] = f2bf(b.w);
    ((u16x8*)out)[i] = v;
}

// ---------------------------------------------------------------------------
// f32 (R x C) row-major -> bf16 (C x R) row-major transpose.
// ---------------------------------------------------------------------------
__global__ __launch_bounds__(256) void transpose_f32_bf16(const float* __restrict__ in,
                                                          u16* __restrict__ out,
                                                          int R, int C) {
    __shared__ u16 t[64][65];
    const int r0 = blockIdx.y << 6, c0 = blockIdx.x << 6;
    const int tid = threadIdx.x;
#pragma unroll
    for (int i = 0; i < 16; i++) {
        int idx = i * 256 + tid;
        int r = idx >> 6, c = idx & 63;
        t[r][c] = f2bf(in[(size_t)(r0 + r) * C + c0 + c]);
    }
    __syncthreads();
#pragma unroll
    for (int i = 0; i < 16; i++) {
        int idx = i * 256 + tid;
        int c = idx >> 6, r = idx & 63;
        out[(size_t)(c0 + c) * R + r0 + r] = t[r][c];
    }
}

// ---------------------------------------------------------------------------
// V transpose: kv (B,K,H,256)[e>=128] -> vT (B,H,128,K)
// ---------------------------------------------------------------------------
__global__ __launch_bounds__(256) void transpose_v(const u16* __restrict__ kv,
                                                   u16* __restrict__ vT) {
    __shared__ u16 t[64][130];
    const int blk = blockIdx.x;
    const int kt = blk & 63, h = (blk >> 6) & 7, b = blk >> 9;
    const int k0 = kt * 64, tid = threadIdx.x;
    const u16* src = kv + ((size_t)(b * 4096 + k0) * 8 + h) * 256 + 128;
#pragma unroll
    for (int i = 0; i < 16; i++) {
        int idx = i * 256 + tid;
        int ki = idx >> 6, e2 = (idx & 63) << 1;
        u32 v = *(const u32*)(src + (size_t)ki * 2048 + e2);
        t[ki][e2] = (u16)v; t[ki][e2 + 1] = (u16)(v >> 16);
    }
    __syncthreads();
    u16* dst = vT + ((size_t)(b * 8 + h)) * 128 * 4096 + k0;
#pragma unroll
    for (int i = 0; i < 16; i++) {
        int idx = i * 256 + tid;
        int e = idx >> 5, ki2 = (idx & 31) << 1;
        u32 v = (u32)t[ki2][e] | ((u32)t[ki2 + 1][e] << 16);
        *(u32*)(dst + (size_t)e * 4096 + ki2) = v;
    }
}

// ---------------------------------------------------------------------------
// GEMM: C(MxN) = A(MxK) * B^T(NxK), bf16 in, fp32 acc.
// 128xNT tile, BK=64, global_load_lds (width 16) staging with global-side
// XOR swizzle: LDS row r chunk p holds global chunk p^(r&7) -> conflict-free
// b128 fragment reads without padding. NT in {128, 64}.
// ---------------------------------------------------------------------------
template <bool OUTF32, int NT>
__global__ __launch_bounds__(256) void gemm_bt(const u16* __restrict__ A,
                                               const u16* __restrict__ B,
                                               void* __restrict__ Cv,
                                               const float* __restrict__ bias,
                                               int M, int N, int K) {
    constexpr int NJ = NT / 32;                 // 16-wide col-frags per wave
    __shared__ __align__(16) u16 As[128 * 64];
    __shared__ __align__(16) u16 Bs[NT * 64];
    const int tid = threadIdx.x;
    const int wave = tid >> 6, lane = tid & 63;
    const int lrow = lane & 15, quad = lane >> 4;
    const int nb = N / NT;
    const int bx = blockIdx.x % nb, by = blockIdx.x / nb;
    const long m0 = (long)by << 7, n0 = (long)bx * NT;
    const int wm = (wave >> 1) << 6, wn = (wave & 1) * (NT / 2);

    const f32x4 fz = {0.f, 0.f, 0.f, 0.f};
    f32x4 acc[4][NJ];
#pragma unroll
    for (int i = 0; i < 4; i++)
#pragma unroll
        for (int j = 0; j < NJ; j++) acc[i][j] = fz;

    // staging: call c covers rows [c*32, c*32+32); wave w handles rows
    // c*32+w*8+(l>>3); global 16B-chunk = (l&7)^(l>>3) (XOR key row&7, and
    // row&7 == l>>3 since c*32+w*8 ≡ 0 mod 8). LDS deposit is lane-ordered:
    // base + l*16B -> row w*8+(l>>3), chunk l&7.
    const int srow = wave * 8 + (lane >> 3);
    const int scol = ((lane & 7) ^ (lane >> 3)) << 3;
    const u16* Ag = A + (m0 + srow) * K + scol;
    const u16* Bg = B + (n0 + srow) * K + scol;
    u16* AsW = &As[wave * 512];
    u16* BsW = &Bs[wave * 512];

    for (int k0 = 0; k0 < K; k0 += 64) {
        __syncthreads();                 // prior iteration's reads done
#pragma unroll
        for (int c = 0; c < 4; c++)
            async16(Ag + (long)c * 32 * K + k0, AsW + c * 2048);
#pragma unroll
        for (int c = 0; c < NT / 32; c++)
            async16(Bg + (long)c * 32 * K + k0, BsW + c * 2048);
        __syncthreads();                 // vmcnt(0) drain: LDS image complete
#pragma unroll
        for (int c = 0; c < 2; c++) {
            bf16x8 af[4], bfr[NJ];
#pragma unroll
            for (int i = 0; i < 4; i++) {
                const int row = wm + i * 16 + lrow;
                af[i] = *(const bf16x8*)&As[row * 64 + (((c * 4 + quad) ^ (row & 7)) << 3)];
            }
#pragma unroll
            for (int j = 0; j < NJ; j++) {
                const int row = wn + j * 16 + lrow;
                bfr[j] = *(const bf16x8*)&Bs[row * 64 + (((c * 4 + quad) ^ (row & 7)) << 3)];
            }
#pragma unroll
            for (int i = 0; i < 4; i++)
#pragma unroll
                for (int j = 0; j < NJ; j++)
                    acc[i][j] = MFMA16(af[i], bfr[j], acc[i][j]);
        }
    }
    // epilogue: C/D layout col=lane&15, row=quad*4+r
#pragma unroll
    for (int j = 0; j < NJ; j++) {
        const long col = n0 + wn + j * 16 + lrow;
        const float bv = bias ? bias[col] : 0.0f;
#pragma unroll
        for (int i = 0; i < 4; i++) {
            const long row = m0 + wm + i * 16 + quad * 4;
#pragma unroll
            for (int r = 0; r < 4; r++) {
                const float v = acc[i][j][r] + bv;
                if (OUTF32) ((float*)Cv)[(row + r) * N + col] = v;
                else        ((u16*)Cv)[(row + r) * N + col] = f2bf(v);
            }
        }
    }
}

// ---------------------------------------------------------------------------
// Split-K flash attention, transposed-MFMA dataflow, XOR-swizzled LDS.
// 512 threads = 8 waves, q-tile 128, kv-tile 64, 4 splits of 1024 kv.
// LDS 49152 B; grid 512 = exactly 2/CU resident.
// blk = (((b*8+h)*4)+qt)*4 + split
// ---------------------------------------------------------------------------
__global__ __launch_bounds__(512) void flash_attn_split(const u16* __restrict__ qb,
                                                        const u16* __restrict__ kvb,
                                                        const u16* __restrict__ vTb,
                                                        float* __restrict__ Opart,
                                                        float* __restrict__ Mpart,
                                                        float* __restrict__ Lpart) {
    __shared__ __align__(16) u16 Ks[64 * 128];    // [kv][dh], blk^(kv&15) swizzle
    __shared__ __align__(16) u16 Vs[128 * 64];    // [dh][kv], blk^(dh&7) swizzle
    __shared__ __align__(16) u16 Ps[8][16 * 64];  // per-wave [q][kv], blk^(q&7)
    const int tid = threadIdx.x, wave = tid >> 6, lane = tid & 63;
    const int lrow = lane & 15, quad = lane >> 4;
    const int blk = blockIdx.x;
    const int split = blk & 3, qt = (blk >> 2) & 3, h = (blk >> 4) & 7, b = blk >> 7;
    const int q0 = qt * 128;
    const int kbase = split * 1024;

    // Q B-frags: B[n=q=lrow][k=dh=quad*8+c*32+j]
    bf16x8 qf[4];
    {
        const u16* qp = qb + (((size_t)(b * 512 + q0 + wave * 16 + lrow) * 8 + h) << 7) + quad * 8;
#pragma unroll
        for (int c = 0; c < 4; c++) qf[c] = *(const bf16x8*)(qp + c * 32);
    }

    const f32x4 fz = {0.f, 0.f, 0.f, 0.f};
    f32x4 oacc[8];           // O^T: oacc[g][r] = O[dh=g*16+quad*4+r][q=lrow]
#pragma unroll
    for (int g = 0; g < 8; g++) oacc[g] = fz;
    float mrow = -1e30f, lsum = 0.f;   // per-lane, q=lrow (replicated across quads)
    const float scale = 0.08838834764831845f;  // 1/sqrt(128)

    // staging: K 64 rows x 16 blks, V 128 rows x 8 blks
    const int kRow = tid >> 4, kBlk = tid & 15;   // rows kRow, kRow+32
    const int vRow = tid >> 3, vBlk = tid & 7;    // rows vRow, vRow+64
    const u16* kg = kvb + (size_t)b * 4096 * 2048 + h * 256 + kBlk * 8;
    const u16* vg = vTb + (size_t)(b * 8 + h) * 128 * 4096 + vBlk * 8;

    for (int k0 = kbase; k0 < kbase + 1024; k0 += 64) {
        __syncthreads();
#pragma unroll
        for (int i = 0; i < 2; i++) {
            const int r = i * 32 + kRow;
            *(bf16x8*)&Ks[r * 128 + ((kBlk ^ (r & 15)) << 3)] =
                *(const bf16x8*)&kg[(size_t)(k0 + r) * 2048];
            const int rv = i * 64 + vRow;
            *(bf16x8*)&Vs[rv * 64 + ((vBlk ^ (rv & 7)) << 3)] =
                *(const bf16x8*)&vg[(size_t)rv * 4096 + k0];
        }
        __syncthreads();

        // S^T: s[t][r] = S[q=lrow][kv = t*16 + quad*4 + r]
        f32x4 s[4];
#pragma unroll
        for (int t = 0; t < 4; t++) {
            f32x4 a = fz;
#pragma unroll
            for (int c = 0; c < 4; c++) {
                const bf16x8 kf = *(const bf16x8*)
                    &Ks[(t * 16 + lrow) * 128 + (((c * 4 + quad) ^ lrow) << 3)];
                a = MFMA16(kf, qf[c], a);
            }
            s[t] = a * scale;
        }

        // per-lane online softmax over 64 kv (16 in-lane + 2 cross-quad shfl)
        float mx = s[0][0];
#pragma unroll
        for (int t = 0; t < 4; t++)
#pragma unroll
            for (int r = 0; r < 4; r++) mx = fmaxf(mx, s[t][r]);
        mx = fmaxf(mx, __shfl_xor(mx, 16));
        mx = fmaxf(mx, __shfl_xor(mx, 32));
        const float mn = fmaxf(mrow, mx);
        const float alpha = __expf(mrow - mn);
        mrow = mn;
        float sum = 0.f;
#pragma unroll
        for (int t = 0; t < 4; t++)
#pragma unroll
            for (int r = 0; r < 4; r++) {
                float p = __expf(s[t][r] - mn);
                s[t][r] = p;
                sum += p;
            }
        sum += __shfl_xor(sum, 16);
        sum += __shfl_xor(sum, 32);
        lsum = lsum * alpha + sum;

        // P pack: lane holds P[q=lrow][kv=t*16+quad*4+r] -> b64 writes, swizzled
        u16* Pw = &Ps[wave][0];
#pragma unroll
        for (int t = 0; t < 4; t++) {
            u16x4 pk;
#pragma unroll
            for (int r = 0; r < 4; r++) pk[r] = f2bf(s[t][r]);
            const int kvo = t * 16 + quad * 4;
            *(u16x4*)&Pw[lrow * 64 + (((kvo >> 3) ^ (lrow & 7)) << 3) + (kvo & 7)] = pk;
        }
        asm volatile("s_waitcnt lgkmcnt(0)" ::: "memory");
        const bf16x8 pf0 = *(const bf16x8*)&Pw[lrow * 64 + ((quad ^ (lrow & 7)) << 3)];
        const bf16x8 pf1 = *(const bf16x8*)&Pw[lrow * 64 + (((4 + quad) ^ (lrow & 7)) << 3)];

        // O^T = O^T*alpha + MFMA(V^T-frag, P-frag)
#pragma unroll
        for (int g = 0; g < 8; g++) {
            f32x4 o = oacc[g] * alpha;
            o = MFMA16(*(const bf16x8*)&Vs[(g * 16 + lrow) * 64 + ((quad ^ (lrow & 7)) << 3)], pf0, o);
            o = MFMA16(*(const bf16x8*)&Vs[(g * 16 + lrow) * 64 + (((4 + quad) ^ (lrow & 7)) << 3)], pf1, o);
            oacc[g] = o;
        }
    }

    // unnormalized partials: Ob[q*128 + dh]
    float* Ob = Opart + (size_t)blk * 16384;
#pragma unroll
    for (int g = 0; g < 8; g++)
        *(f32x4*)&Ob[(wave * 16 + lrow) * 128 + g * 16 + quad * 4] = oacc[g];
    if (quad == 0) {
        const int row = blk * 128 + wave * 16 + lrow;
        Mpart[row] = mrow;
        Lpart[row] = lsum;
    }
}

// ---------------------------------------------------------------------------
// Combine 4 split partials -> obuf (B,Q,H,128) bf16.
// grid 128 (= (b*8+h)*4+qt), 512 threads: 128 rows x 4 col-groups of 32.
// ---------------------------------------------------------------------------
__global__ __launch_bounds__(512) void combine_attn(const float* __restrict__ Opart,
                                                    const float* __restrict__ Mpart,
                                                    const float* __restrict__ Lpart,
                                                    u16* __restrict__ ob) {
    const int c = blockIdx.x;
    const int qt = c & 3, h = (c >> 2) & 7, b = c >> 5;
    const int lr = threadIdx.x >> 2, cg = (threadIdx.x & 3) * 32;
    float ms[4], w[4];
    float m = -1e30f;
#pragma unroll
    for (int s = 0; s < 4; s++) { ms[s] = Mpart[(c * 4 + s) * 128 + lr]; m = fmaxf(m, ms[s]); }
    float l = 0.f;
#pragma unroll
    for (int s = 0; s < 4; s++) { w[s] = __expf(ms[s] - m); l += w[s] * Lpart[(c * 4 + s) * 128 + lr]; }
    const float inv = 1.f / l;
#pragma unroll
    for (int s = 0; s < 4; s++) w[s] *= inv;
    const size_t orow = ((size_t)(b * 512 + qt * 128 + lr) * 8 + h) << 7;
#pragma unroll
    for (int j = 0; j < 4; j++) {
        f32x4 a0 = {0.f, 0.f, 0.f, 0.f}, a1 = a0;
#pragma unroll
        for (int s = 0; s < 4; s++) {
            const f32x4* p = (const f32x4*)(Opart + ((size_t)(c * 4 + s)) * 16384 + (size_t)lr * 128 + cg + j * 8);
            a0 += p[0] * w[s];
            a1 += p[1] * w[s];
        }
        u16x8 v;
#pragma unroll
        for (int i = 0; i < 4; i++) { v[i] = f2bf(a0[i]); v[4 + i] = f2bf(a1[i]); }
        *(u16x8*)&ob[orow + cg + j * 8] = v;
    }
}

// ---------------------------------------------------------------------------
extern "C" void kernel_launch(void* const* d_in, const int* in_sizes, int n_in,
                              void* d_out, int out_size, void* d_ws, size_t ws_size,
                              hipStream_t stream) {
    const float* inq   = (const float*)d_in[0];
    const float* inkv  = (const float*)d_in[1];
    const float* Wq    = (const float*)d_in[2];
    const float* Wkv   = (const float*)d_in[3];
    const float* Wproj = (const float*)d_in[4];
    const float* bproj = (const float*)d_in[5];
    float* out = (float*)d_out;

    u16* WqT    = (u16*)d_ws;                          // 1M elems
    u16* WkvT   = WqT + (size_t)1024 * 1024;           // 2M
    u16* WprojT = WkvT + (size_t)2048 * 1024;          // 1M
    u16* Aq     = WprojT + (size_t)1024 * 1024;        // 2M   bf16(inputs_q); dead after q-gemm
    u16* Akv    = Aq + (size_t)2048 * 1024;            // 16M  bf16(inputs_kv); dead after kv-gemm
    u16* qbuf   = Akv + (size_t)16384 * 1024;          // 2M   (B,Q,H,DH)
    u16* kvbuf  = qbuf + (size_t)2048 * 1024;          // 32M  (B,K,H,2DH)
    u16* vTbuf  = kvbuf + (size_t)16384 * 2048;        // 16M  (B,H,DH,K)
    u16* obuf   = vTbuf + (size_t)32 * 128 * 4096;     // 2M   (B,Q,H,DH)

    // flash partials alias dead input-convert regions
    float* Opart = (float*)Akv;                        // 512*16384 f32 = 32 MB
    float* Mpart = (float*)Aq;                         // 64K f32
    float* Lpart = Mpart + 65536;                      // 64K f32

    convert_f32_bf16<<<1024, 256, 0, stream>>>(inq, Aq, 262144);
    convert_f32_bf16<<<8192, 256, 0, stream>>>(inkv, Akv, 2097152);
    transpose_f32_bf16<<<dim3(16, 16), 256, 0, stream>>>(Wq, WqT, 1024, 1024);
    transpose_f32_bf16<<<dim3(32, 16), 256, 0, stream>>>(Wkv, WkvT, 1024, 2048);
    transpose_f32_bf16<<<dim3(16, 16), 256, 0, stream>>>(Wproj, WprojT, 1024, 1024);

    gemm_bt<false, 64><<<16 * 16, 256, 0, stream>>>(Aq, WqT, qbuf, nullptr, 2048, 1024, 1024);
    gemm_bt<false, 128><<<128 * 16, 256, 0, stream>>>(Akv, WkvT, kvbuf, nullptr, 16384, 2048, 1024);

    transpose_v<<<2048, 256, 0, stream>>>(kvbuf, vTbuf);

    flash_attn_split<<<512, 512, 0, stream>>>(qbuf, kvbuf, vTbuf, Opart, Mpart, Lpart);
    combine_attn<<<128, 512, 0, stream>>>(Opart, Mpart, Lpart, obuf);

    gemm_bt<true, 64><<<16 * 16, 256, 0, stream>>>(obuf, WprojT, (void*)out, bproj, 2048, 1024, 1024);
}

// Round 8
// 313.223 us; speedup vs baseline: 1.6110x; 1.0247x over previous
//
#include <hip/hip_runtime.h>
#include <hip/hip_bf16.h>
#include <cstdint>

typedef unsigned short u16;
typedef unsigned int u32;
typedef __bf16 bf16x8 __attribute__((ext_vector_type(8)));
typedef u16 u16x8 __attribute__((ext_vector_type(8)));
typedef u16 u16x4 __attribute__((ext_vector_type(4)));
typedef float f32x4 __attribute__((ext_vector_type(4)));

#define MFMA16(a, b, c) __builtin_amdgcn_mfma_f32_16x16x32_bf16(a, b, c, 0, 0, 0)

__device__ __forceinline__ void async16(const void* g, void* s) {
    __builtin_amdgcn_global_load_lds((const __attribute__((address_space(1))) void*)g,
                                     (__attribute__((address_space(3))) void*)s, 16, 0, 0);
}

__device__ __forceinline__ u16 f2bf(float f) {
    u32 u; __builtin_memcpy(&u, &f, 4);
    u = u + 0x7fffu + ((u >> 16) & 1u);
    return (u16)(u >> 16);
}

// ---------------------------------------------------------------------------
// Fused input converts: blocks [0,1024) -> inq (262144 chunks),
// blocks [1024,9216) -> inkv (2097152 chunks). 8 f32 -> 8 bf16 per thread.
// ---------------------------------------------------------------------------
__global__ __launch_bounds__(256) void convert_inputs(const float* __restrict__ inq,
                                                      u16* __restrict__ Aq,
                                                      const float* __restrict__ inkv,
                                                      u16* __restrict__ Akv) {
    const int blk = blockIdx.x;
    const float* in; u16* out; size_t i;
    if (blk < 1024) { in = inq;  out = Aq;  i = (size_t)blk * 256 + threadIdx.x; }
    else            { in = inkv; out = Akv; i = (size_t)(blk - 1024) * 256 + threadIdx.x; }
    const float4* p = (const float4*)in + i * 2;
    const float4 a = p[0], b = p[1];
    u16x8 v;
    v[0] = f2bf(a.x); v[1] = f2bf(a.y); v[2] = f2bf(a.z); v[3] = f2bf(a.w);
    v[4] = f2bf(b.x); v[5] = f2bf(b.y); v[6] = f2bf(b.z); v[7] = f2bf(b.w);
    ((u16x8*)out)[i] = v;
}

// ---------------------------------------------------------------------------
// Fused weight prep: f32 (R x C) -> bf16 (C x R) transpose for Wq/Wkv/Wproj.
// blocks [0,256) Wq(1024x1024), [256,768) Wkv(1024x2048), [768,1024) Wproj.
// ---------------------------------------------------------------------------
__global__ __launch_bounds__(256) void prep_weights(const float* __restrict__ Wq,  u16* __restrict__ WqT,
                                                    const float* __restrict__ Wkv, u16* __restrict__ WkvT,
                                                    const float* __restrict__ Wp,  u16* __restrict__ WpT) {
    __shared__ u16 t[64][65];
    const int blk = blockIdx.x;
    const float* in; u16* out; int R, C, bx, by;
    if (blk < 256)      { in = Wq;  out = WqT;  R = 1024; C = 1024; bx = blk & 15;  by = blk >> 4; }
    else if (blk < 768) { in = Wkv; out = WkvT; R = 1024; C = 2048; bx = (blk - 256) & 31; by = (blk - 256) >> 5; }
    else                { in = Wp;  out = WpT;  R = 1024; C = 1024; bx = (blk - 768) & 15; by = (blk - 768) >> 4; }
    const int r0 = by << 6, c0 = bx << 6;
    const int tid = threadIdx.x;
#pragma unroll
    for (int i = 0; i < 16; i++) {
        int idx = i * 256 + tid;
        int r = idx >> 6, c = idx & 63;
        t[r][c] = f2bf(in[(size_t)(r0 + r) * C + c0 + c]);
    }
    __syncthreads();
#pragma unroll
    for (int i = 0; i < 16; i++) {
        int idx = i * 256 + tid;
        int c = idx >> 6, r = idx & 63;
        out[(size_t)(c0 + c) * R + r0 + r] = t[r][c];
    }
}

// ---------------------------------------------------------------------------
// GEMM: C(MxN) = A(MxK) * B^T(NxK), bf16 in, fp32 acc.
// 128xNT tile, BK=64, global_load_lds (width 16) staging with global-side
// XOR swizzle (conflict-free b128 reads, zero padding). NT in {128, 64}.
// VFUSE (kv projection): odd bx tiles are the V-half of a head (N layout
// h*256 + colh, NT=128) -> write accumulators transposed to Vt[b,h,dh,kv]
// and skip the C write.
// ---------------------------------------------------------------------------
template <bool OUTF32, int NT, bool VFUSE>
__global__ __launch_bounds__(256) void gemm_bt(const u16* __restrict__ A,
                                               const u16* __restrict__ B,
                                               void* __restrict__ Cv,
                                               const float* __restrict__ bias,
                                               u16* __restrict__ Vt,
                                               int M, int N, int K) {
    constexpr int NJ = NT / 32;                 // 16-wide col-frags per wave
    __shared__ __align__(16) u16 As[128 * 64];
    __shared__ __align__(16) u16 Bs[NT * 64];
    const int tid = threadIdx.x;
    const int wave = tid >> 6, lane = tid & 63;
    const int lrow = lane & 15, quad = lane >> 4;
    const int nb = N / NT;
    const int bx = blockIdx.x % nb, by = blockIdx.x / nb;
    const long m0 = (long)by << 7, n0 = (long)bx * NT;
    const int wm = (wave >> 1) << 6, wn = (wave & 1) * (NT / 2);

    const f32x4 fz = {0.f, 0.f, 0.f, 0.f};
    f32x4 acc[4][NJ];
#pragma unroll
    for (int i = 0; i < 4; i++)
#pragma unroll
        for (int j = 0; j < NJ; j++) acc[i][j] = fz;

    // staging: call c covers rows [c*32, c*32+32); wave w handles rows
    // c*32+w*8+(l>>3); global 16B-chunk = (l&7)^(l>>3). LDS deposit is
    // lane-ordered: base + l*16B -> row w*8+(l>>3), chunk l&7.
    const int srow = wave * 8 + (lane >> 3);
    const int scol = ((lane & 7) ^ (lane >> 3)) << 3;
    const u16* Ag = A + (m0 + srow) * K + scol;
    const u16* Bg = B + (n0 + srow) * K + scol;
    u16* AsW = &As[wave * 512];
    u16* BsW = &Bs[wave * 512];

    for (int k0 = 0; k0 < K; k0 += 64) {
        __syncthreads();                 // prior iteration's reads done
#pragma unroll
        for (int c = 0; c < 4; c++)
            async16(Ag + (long)c * 32 * K + k0, AsW + c * 2048);
#pragma unroll
        for (int c = 0; c < NT / 32; c++)
            async16(Bg + (long)c * 32 * K + k0, BsW + c * 2048);
        __syncthreads();                 // vmcnt(0) drain: LDS image complete
#pragma unroll
        for (int c = 0; c < 2; c++) {
            bf16x8 af[4], bfr[NJ];
#pragma unroll
            for (int i = 0; i < 4; i++) {
                const int row = wm + i * 16 + lrow;
                af[i] = *(const bf16x8*)&As[row * 64 + (((c * 4 + quad) ^ (row & 7)) << 3)];
            }
#pragma unroll
            for (int j = 0; j < NJ; j++) {
                const int row = wn + j * 16 + lrow;
                bfr[j] = *(const bf16x8*)&Bs[row * 64 + (((c * 4 + quad) ^ (row & 7)) << 3)];
            }
#pragma unroll
            for (int i = 0; i < 4; i++)
#pragma unroll
                for (int j = 0; j < NJ; j++)
                    acc[i][j] = MFMA16(af[i], bfr[j], acc[i][j]);
        }
    }
    // epilogue: C/D layout col=lane&15, row=quad*4+r
    if (VFUSE && (bx & 1)) {
        // V-half tile: write transposed to Vt[((b*8+h)*128+dh)*4096 + kv]
#pragma unroll
        for (int j = 0; j < NJ; j++) {
            const int col = (int)n0 + wn + j * 16 + lrow;
            const int h = col >> 8, dh = (col & 255) - 128;
#pragma unroll
            for (int i = 0; i < 4; i++) {
                const int row = (int)m0 + wm + i * 16 + quad * 4;
                const int b = row >> 12, kv = row & 4095;
                u16x4 pk;
#pragma unroll
                for (int r = 0; r < 4; r++) pk[r] = f2bf(acc[i][j][r]);
                *(u16x4*)&Vt[(((size_t)b * 8 + h) * 128 + dh) * 4096 + kv] = pk;
            }
        }
        return;
    }
#pragma unroll
    for (int j = 0; j < NJ; j++) {
        const long col = n0 + wn + j * 16 + lrow;
        const float bv = bias ? bias[col] : 0.0f;
#pragma unroll
        for (int i = 0; i < 4; i++) {
            const long row = m0 + wm + i * 16 + quad * 4;
#pragma unroll
            for (int r = 0; r < 4; r++) {
                const float v = acc[i][j][r] + bv;
                if (OUTF32) ((float*)Cv)[(row + r) * N + col] = v;
                else        ((u16*)Cv)[(row + r) * N + col] = f2bf(v);
            }
        }
    }
}

// ---------------------------------------------------------------------------
// Split-K flash attention, transposed-MFMA dataflow, XOR-swizzled LDS.
// 512 threads = 8 waves, q-tile 128, kv-tile 64, 4 splits of 1024 kv.
// LDS 49152 B; grid 512 = exactly 2/CU resident.
// blk = (((b*8+h)*4)+qt)*4 + split
// ---------------------------------------------------------------------------
__global__ __launch_bounds__(512) void flash_attn_split(const u16* __restrict__ qb,
                                                        const u16* __restrict__ kvb,
                                                        const u16* __restrict__ vTb,
                                                        float* __restrict__ Opart,
                                                        float* __restrict__ Mpart,
                                                        float* __restrict__ Lpart) {
    __shared__ __align__(16) u16 Ks[64 * 128];    // [kv][dh], blk^(kv&15) swizzle
    __shared__ __align__(16) u16 Vs[128 * 64];    // [dh][kv], blk^(dh&7) swizzle
    __shared__ __align__(16) u16 Ps[8][16 * 64];  // per-wave [q][kv], blk^(q&7)
    const int tid = threadIdx.x, wave = tid >> 6, lane = tid & 63;
    const int lrow = lane & 15, quad = lane >> 4;
    const int blk = blockIdx.x;
    const int split = blk & 3, qt = (blk >> 2) & 3, h = (blk >> 4) & 7, b = blk >> 7;
    const int q0 = qt * 128;
    const int kbase = split * 1024;

    // Q B-frags: B[n=q=lrow][k=dh=quad*8+c*32+j]
    bf16x8 qf[4];
    {
        const u16* qp = qb + (((size_t)(b * 512 + q0 + wave * 16 + lrow) * 8 + h) << 7) + quad * 8;
#pragma unroll
        for (int c = 0; c < 4; c++) qf[c] = *(const bf16x8*)(qp + c * 32);
    }

    const f32x4 fz = {0.f, 0.f, 0.f, 0.f};
    f32x4 oacc[8];           // O^T: oacc[g][r] = O[dh=g*16+quad*4+r][q=lrow]
#pragma unroll
    for (int g = 0; g < 8; g++) oacc[g] = fz;
    float mrow = -1e30f, lsum = 0.f;   // per-lane, q=lrow (replicated across quads)
    const float scale = 0.08838834764831845f;  // 1/sqrt(128)

    // staging: K 64 rows x 16 blks, V 128 rows x 8 blks
    const int kRow = tid >> 4, kBlk = tid & 15;   // rows kRow, kRow+32
    const int vRow = tid >> 3, vBlk = tid & 7;    // rows vRow, vRow+64
    const u16* kg = kvb + (size_t)b * 4096 * 2048 + h * 256 + kBlk * 8;
    const u16* vg = vTb + (size_t)(b * 8 + h) * 128 * 4096 + vBlk * 8;

    for (int k0 = kbase; k0 < kbase + 1024; k0 += 64) {
        __syncthreads();
#pragma unroll
        for (int i = 0; i < 2; i++) {
            const int r = i * 32 + kRow;
            *(bf16x8*)&Ks[r * 128 + ((kBlk ^ (r & 15)) << 3)] =
                *(const bf16x8*)&kg[(size_t)(k0 + r) * 2048];
            const int rv = i * 64 + vRow;
            *(bf16x8*)&Vs[rv * 64 + ((vBlk ^ (rv & 7)) << 3)] =
                *(const bf16x8*)&vg[(size_t)rv * 4096 + k0];
        }
        __syncthreads();

        // S^T: s[t][r] = S[q=lrow][kv = t*16 + quad*4 + r]
        f32x4 s[4];
#pragma unroll
        for (int t = 0; t < 4; t++) {
            f32x4 a = fz;
#pragma unroll
            for (int c = 0; c < 4; c++) {
                const bf16x8 kf = *(const bf16x8*)
                    &Ks[(t * 16 + lrow) * 128 + (((c * 4 + quad) ^ lrow) << 3)];
                a = MFMA16(kf, qf[c], a);
            }
            s[t] = a * scale;
        }

        // per-lane online softmax over 64 kv (16 in-lane + 2 cross-quad shfl)
        float mx = s[0][0];
#pragma unroll
        for (int t = 0; t < 4; t++)
#pragma unroll
            for (int r = 0; r < 4; r++) mx = fmaxf(mx, s[t][r]);
        mx = fmaxf(mx, __shfl_xor(mx, 16));
        mx = fmaxf(mx, __shfl_xor(mx, 32));
        const float mn = fmaxf(mrow, mx);
        const float alpha = __expf(mrow - mn);
        mrow = mn;
        float sum = 0.f;
#pragma unroll
        for (int t = 0; t < 4; t++)
#pragma unroll
            for (int r = 0; r < 4; r++) {
                float p = __expf(s[t][r] - mn);
                s[t][r] = p;
                sum += p;
            }
        sum += __shfl_xor(sum, 16);
        sum += __shfl_xor(sum, 32);
        lsum = lsum * alpha + sum;

        // P pack: lane holds P[q=lrow][kv=t*16+quad*4+r] -> b64 writes, swizzled
        u16* Pw = &Ps[wave][0];
#pragma unroll
        for (int t = 0; t < 4; t++) {
            u16x4 pk;
#pragma unroll
            for (int r = 0; r < 4; r++) pk[r] = f2bf(s[t][r]);
            const int kvo = t * 16 + quad * 4;
            *(u16x4*)&Pw[lrow * 64 + (((kvo >> 3) ^ (lrow & 7)) << 3) + (kvo & 7)] = pk;
        }
        asm volatile("s_waitcnt lgkmcnt(0)" ::: "memory");
        const bf16x8 pf0 = *(const bf16x8*)&Pw[lrow * 64 + ((quad ^ (lrow & 7)) << 3)];
        const bf16x8 pf1 = *(const bf16x8*)&Pw[lrow * 64 + (((4 + quad) ^ (lrow & 7)) << 3)];

        // O^T = O^T*alpha + MFMA(V^T-frag, P-frag)
#pragma unroll
        for (int g = 0; g < 8; g++) {
            f32x4 o = oacc[g] * alpha;
            o = MFMA16(*(const bf16x8*)&Vs[(g * 16 + lrow) * 64 + ((quad ^ (lrow & 7)) << 3)], pf0, o);
            o = MFMA16(*(const bf16x8*)&Vs[(g * 16 + lrow) * 64 + (((4 + quad) ^ (lrow & 7)) << 3)], pf1, o);
            oacc[g] = o;
        }
    }

    // unnormalized partials: Ob[q*128 + dh]
    float* Ob = Opart + (size_t)blk * 16384;
#pragma unroll
    for (int g = 0; g < 8; g++)
        *(f32x4*)&Ob[(wave * 16 + lrow) * 128 + g * 16 + quad * 4] = oacc[g];
    if (quad == 0) {
        const int row = blk * 128 + wave * 16 + lrow;
        Mpart[row] = mrow;
        Lpart[row] = lsum;
    }
}

// ---------------------------------------------------------------------------
// Combine 4 split partials -> obuf (B,Q,H,128) bf16.
// grid 128 (= (b*8+h)*4+qt), 512 threads: 128 rows x 4 col-groups of 32.
// ---------------------------------------------------------------------------
__global__ __launch_bounds__(512) void combine_attn(const float* __restrict__ Opart,
                                                    const float* __restrict__ Mpart,
                                                    const float* __restrict__ Lpart,
                                                    u16* __restrict__ ob) {
    const int c = blockIdx.x;
    const int qt = c & 3, h = (c >> 2) & 7, b = c >> 5;
    const int lr = threadIdx.x >> 2, cg = (threadIdx.x & 3) * 32;
    float ms[4], w[4];
    float m = -1e30f;
#pragma unroll
    for (int s = 0; s < 4; s++) { ms[s] = Mpart[(c * 4 + s) * 128 + lr]; m = fmaxf(m, ms[s]); }
    float l = 0.f;
#pragma unroll
    for (int s = 0; s < 4; s++) { w[s] = __expf(ms[s] - m); l += w[s] * Lpart[(c * 4 + s) * 128 + lr]; }
    const float inv = 1.f / l;
#pragma unroll
    for (int s = 0; s < 4; s++) w[s] *= inv;
    const size_t orow = ((size_t)(b * 512 + qt * 128 + lr) * 8 + h) << 7;
#pragma unroll
    for (int j = 0; j < 4; j++) {
        f32x4 a0 = {0.f, 0.f, 0.f, 0.f}, a1 = a0;
#pragma unroll
        for (int s = 0; s < 4; s++) {
            const f32x4* p = (const f32x4*)(Opart + ((size_t)(c * 4 + s)) * 16384 + (size_t)lr * 128 + cg + j * 8);
            a0 += p[0] * w[s];
            a1 += p[1] * w[s];
        }
        u16x8 v;
#pragma unroll
        for (int i = 0; i < 4; i++) { v[i] = f2bf(a0[i]); v[4 + i] = f2bf(a1[i]); }
        *(u16x8*)&ob[orow + cg + j * 8] = v;
    }
}

// ---------------------------------------------------------------------------
extern "C" void kernel_launch(void* const* d_in, const int* in_sizes, int n_in,
                              void* d_out, int out_size, void* d_ws, size_t ws_size,
                              hipStream_t stream) {
    const float* inq   = (const float*)d_in[0];
    const float* inkv  = (const float*)d_in[1];
    const float* Wq    = (const float*)d_in[2];
    const float* Wkv   = (const float*)d_in[3];
    const float* Wproj = (const float*)d_in[4];
    const float* bproj = (const float*)d_in[5];
    float* out = (float*)d_out;

    u16* WqT    = (u16*)d_ws;                          // 1M elems
    u16* WkvT   = WqT + (size_t)1024 * 1024;           // 2M
    u16* WprojT = WkvT + (size_t)2048 * 1024;          // 1M
    u16* Aq     = WprojT + (size_t)1024 * 1024;        // 2M   bf16(inputs_q); dead after q-gemm
    u16* Akv    = Aq + (size_t)2048 * 1024;            // 16M  bf16(inputs_kv); dead after kv-gemm
    u16* qbuf   = Akv + (size_t)16384 * 1024;          // 2M   (B,Q,H,DH)
    u16* kvbuf  = qbuf + (size_t)2048 * 1024;          // 32M  (B,K,H,2DH) K-half valid
    u16* vTbuf  = kvbuf + (size_t)16384 * 2048;        // 16M  (B,H,DH,K)
    u16* obuf   = vTbuf + (size_t)32 * 128 * 4096;     // 2M   (B,Q,H,DH)

    // flash partials alias dead input-convert regions
    float* Opart = (float*)Akv;                        // 512*16384 f32 = 32 MB
    float* Mpart = (float*)Aq;                         // 64K f32
    float* Lpart = Mpart + 65536;                      // 64K f32

    convert_inputs<<<9216, 256, 0, stream>>>(inq, Aq, inkv, Akv);
    prep_weights<<<1024, 256, 0, stream>>>(Wq, WqT, Wkv, WkvT, Wproj, WprojT);

    gemm_bt<false, 64, false><<<16 * 16, 256, 0, stream>>>(Aq, WqT, qbuf, nullptr, nullptr, 2048, 1024, 1024);
    gemm_bt<false, 128, true><<<128 * 16, 256, 0, stream>>>(Akv, WkvT, kvbuf, nullptr, vTbuf, 16384, 2048, 1024);

    flash_attn_split<<<512, 512, 0, stream>>>(qbuf, kvbuf, vTbuf, Opart, Mpart, Lpart);
    combine_attn<<<128, 512, 0, stream>>>(Opart, Mpart, Lpart, obuf);

    gemm_bt<true, 64, false><<<16 * 16, 256, 0, stream>>>(obuf, WprojT, (void*)out, bproj, nullptr, 2048, 1024, 1024);
}